// Round 7
// baseline (108.514 us; speedup 1.0000x reference)
//
#include <hip/hip_runtime.h>
#include <hip/hip_bf16.h>
#include <math.h>

#define BDIM 32
#define TDIM 1025
#define DDIM 768
#define GRIDW 32
#define TPATCH 1024
#define SCALE 8.0f
#define EPSLN 1e-5f
#define NROW (BDIM * TDIM)   // 32800
#define VTLD 1088            // vT row stride (elements, 16B-aligned, >= 1024+64)
#define LDP  72              // LDS row stride (elements; 144B = 16B-aligned)
#define NTILES 17

typedef __attribute__((ext_vector_type(8))) short short8v;   // 8 bf16 (4 VGPRs)
typedef __attribute__((ext_vector_type(4))) float f32x4;     // MFMA C/D frag

__device__ __forceinline__ unsigned short f2bf(float f) {
    unsigned int u = __float_as_uint(f);
    u += 0x7FFFu + ((u >> 16) & 1u);      // round-to-nearest-even
    return (unsigned short)(u >> 16);
}

__device__ __forceinline__ short8v pack8(float4 a, float4 b) {
    union { short8v v; unsigned short s[8]; } u;
    u.s[0] = f2bf(a.x); u.s[1] = f2bf(a.y); u.s[2] = f2bf(a.z); u.s[3] = f2bf(a.w);
    u.s[4] = f2bf(b.x); u.s[5] = f2bf(b.y); u.s[6] = f2bf(b.z); u.s[7] = f2bf(b.w);
    return u.v;
}

// ---- 16-lane (DPP-row) reductions on the VALU pipe (no LDS latency) ----
template<int CTRL>
__device__ __forceinline__ float dpp_f(float x) {
    return __int_as_float(__builtin_amdgcn_update_dpp(
        __float_as_int(x), __float_as_int(x), CTRL, 0xF, 0xF, true));
}
__device__ __forceinline__ float red16_max(float x) {
    x = fmaxf(x, dpp_f<0xB1>(x));    // quad_perm xor1
    x = fmaxf(x, dpp_f<0x4E>(x));    // quad_perm xor2
    x = fmaxf(x, dpp_f<0x124>(x));   // row_ror:4
    x = fmaxf(x, dpp_f<0x128>(x));   // row_ror:8
    return x;
}
__device__ __forceinline__ float red16_sum(float x) {
    x += dpp_f<0xB1>(x);
    x += dpp_f<0x4E>(x);
    x += dpp_f<0x124>(x);
    x += dpp_f<0x128>(x);
    return x;
}

// ---------------------------------------------------------------------------
// Kernel 0: W -> bf16, transposed: wT[c][k], c = 0..191 (q|k|v), k = 0..767
// ---------------------------------------------------------------------------
__global__ __launch_bounds__(256) void prep_w_kernel(
    const float* __restrict__ Wq, const float* __restrict__ Wk,
    const float* __restrict__ Wv, unsigned short* __restrict__ wT)
{
    const int c = blockIdx.x;                  // 0..191
    const float* W = (c < 64) ? Wq : (c < 128) ? Wk : Wv;
    const int cc = c & 63;
    for (int k = threadIdx.x; k < DDIM; k += 256)
        wT[(size_t)c * DDIM + k] = f2bf(W[(size_t)k * 64 + cc]);
}

// ---------------------------------------------------------------------------
// Kernel 1: MFMA QKV projection + fused LN + heads.
// 513 blocks x 4 waves. Block: 64 rows x 192 cols, BK=64 (12 K-steps).
// Per step: barrier -> issue loads(k+1) -> compute(k) -> LDS-write(k+1) into
// buf^1 (vmcnt wait hidden under 24 MFMAs) -> barrier. One barrier per step.
// ---------------------------------------------------------------------------
__global__ __launch_bounds__(256) void qkv_tile_kernel(
    const float* __restrict__ x, const unsigned short* __restrict__ wT,
    const float* __restrict__ gq, const float* __restrict__ bq,
    const float* __restrict__ gk, const float* __restrict__ bk,
    const float* __restrict__ Wsig, const float* __restrict__ bsig,
    const float* __restrict__ Wa, const float* __restrict__ ba,
    unsigned short* __restrict__ qb, unsigned short* __restrict__ kb,
    unsigned short* __restrict__ vb,
    float* __restrict__ a8, float* __restrict__ isx, float* __restrict__ isy)
{
    __shared__ unsigned short As[2][64][LDP];    // 18.4 KB
    __shared__ unsigned short Bs[2][192][LDP];   // 55.3 KB

    const int t  = threadIdx.x;
    const int wv = t >> 6;
    const int ln = t & 63;
    const int lq = ln >> 4;
    const int lr = ln & 15;
    const int tok0 = blockIdx.x * 64;           // flat row (b*TDIM + ti)

    // staging maps: lin = t + 256*j -> row = lin>>3, 16B-chunk = lin&7
    const float* la_ptr[2];
    const unsigned short* lb_ptr[6];
#pragma unroll
    for (int j = 0; j < 2; ++j) {
        int lin = t + 256 * j;
        la_ptr[j] = x + (size_t)min(tok0 + (lin >> 3), NROW - 1) * DDIM + (lin & 7) * 8;
    }
#pragma unroll
    for (int j = 0; j < 6; ++j) {
        int lin = t + 256 * j;
        lb_ptr[j] = wT + (size_t)(lin >> 3) * DDIM + (lin & 7) * 8;
    }

    float4  raf[2][2];
    short8v rbv[6];

#define QLOAD(K0)                                                              \
    do {                                                                       \
        _Pragma("unroll") for (int j = 0; j < 2; ++j) {                        \
            raf[j][0] = *(const float4*)(la_ptr[j] + (K0));                    \
            raf[j][1] = *(const float4*)(la_ptr[j] + (K0) + 4);                \
        }                                                                      \
        _Pragma("unroll") for (int j = 0; j < 6; ++j)                          \
            rbv[j] = *(const short8v*)(lb_ptr[j] + (K0));                      \
    } while (0)

#define QSTORE(BUF)                                                            \
    do {                                                                       \
        _Pragma("unroll") for (int j = 0; j < 2; ++j) {                        \
            int lin = t + 256 * j;                                             \
            *(short8v*)&As[BUF][lin >> 3][(lin & 7) * 8] =                     \
                pack8(raf[j][0], raf[j][1]);                                   \
        }                                                                      \
        _Pragma("unroll") for (int j = 0; j < 6; ++j) {                        \
            int lin = t + 256 * j;                                             \
            *(short8v*)&Bs[BUF][lin >> 3][(lin & 7) * 8] = rbv[j];             \
        }                                                                      \
    } while (0)

    f32x4 acc[12];
#pragma unroll
    for (int ni = 0; ni < 12; ++ni) acc[ni] = (f32x4){0.f, 0.f, 0.f, 0.f};

    // prologue: stage k-step 0
    QLOAD(0);
    QSTORE(0);
    __syncthreads();

#pragma unroll
    for (int ks = 0; ks < 12; ++ks) {
        const int buf = ks & 1;
        if (ks + 1 < 12) QLOAD((ks + 1) * 64);          // issue early
        short8v af0 = *(const short8v*)&As[buf][wv * 16 + lr][lq * 8];
        short8v af1 = *(const short8v*)&As[buf][wv * 16 + lr][32 + lq * 8];
#pragma unroll
        for (int ni = 0; ni < 12; ++ni) {
            short8v bf0 = *(const short8v*)&Bs[buf][16 * ni + lr][lq * 8];
            acc[ni] = __builtin_amdgcn_mfma_f32_16x16x32_bf16(af0, bf0, acc[ni], 0, 0, 0);
            short8v bf1 = *(const short8v*)&Bs[buf][16 * ni + lr][32 + lq * 8];
            acc[ni] = __builtin_amdgcn_mfma_f32_16x16x32_bf16(af1, bf1, acc[ni], 0, 0, 0);
        }
        if (ks + 1 < 12) QSTORE(buf ^ 1);               // vmcnt wait lands here
        __syncthreads();
    }
#undef QLOAD
#undef QSTORE

    // ---- epilogue: LN(q), LN(k), alpha/sigma head, writes ----
    float gqv[4], bqv[4], gkv[4], bkv[4], wav[4], ws0[4], ws1[4];
#pragma unroll
    for (int ni = 0; ni < 4; ++ni) {
        int c = lr + 16 * ni;
        gqv[ni] = gq[c]; bqv[ni] = bq[c];
        gkv[ni] = gk[c]; bkv[ni] = bk[c];
        wav[ni] = Wa[c];
        ws0[ni] = Wsig[2 * c];
        ws1[ni] = Wsig[2 * c + 1];
    }
    const float ba0 = ba[0], bs0 = bsig[0], bs1 = bsig[1];

#pragma unroll
    for (int reg = 0; reg < 4; ++reg) {
        const int tokr = tok0 + wv * 16 + lq * 4 + reg;

        float s1 = 0.f, s2 = 0.f;
#pragma unroll
        for (int ni = 0; ni < 4; ++ni) {
            float v = acc[ni][reg];
            s1 += v; s2 += v * v;
        }
        s1 = red16_sum(s1);
        s2 = red16_sum(s2);
        float mean = s1 * (1.f / 64.f);
        float var  = s2 * (1.f / 64.f) - mean * mean;
        float rstd = rsqrtf(var + EPSLN);
        float qn[4];
#pragma unroll
        for (int ni = 0; ni < 4; ++ni)
            qn[ni] = (acc[ni][reg] - mean) * rstd * gqv[ni] + bqv[ni];

        s1 = 0.f; s2 = 0.f;
#pragma unroll
        for (int ni = 0; ni < 4; ++ni) {
            float v = acc[4 + ni][reg];
            s1 += v; s2 += v * v;
        }
        s1 = red16_sum(s1);
        s2 = red16_sum(s2);
        mean = s1 * (1.f / 64.f);
        var  = s2 * (1.f / 64.f) - mean * mean;
        rstd = rsqrtf(var + EPSLN);
        float kn[4];
#pragma unroll
        for (int ni = 0; ni < 4; ++ni)
            kn[ni] = (acc[4 + ni][reg] - mean) * rstd * gkv[ni] + bkv[ni];

        float da = 0.f, d0 = 0.f, d1 = 0.f;
#pragma unroll
        for (int ni = 0; ni < 4; ++ni) {
            da += qn[ni] * wav[ni];
            d0 += qn[ni] * ws0[ni];
            d1 += qn[ni] * ws1[ni];
        }
        da = red16_sum(da);
        d0 = red16_sum(d0);
        d1 = red16_sum(d1);

        if (tokr < NROW) {
            size_t base = (size_t)tokr * 64;
            int bidx = tokr / TDIM;
            int ti   = tokr - bidx * TDIM;
#pragma unroll
            for (int ni = 0; ni < 4; ++ni) {
                int c = lr + 16 * ni;
                qb[base + c] = f2bf(qn[ni]);
                kb[base + c] = f2bf(kn[ni]);
                vb[base + c] = f2bf(acc[8 + ni][reg]);
            }
            if (lr == 0 && ti >= 1) {
                int p = bidx * TPATCH + ti - 1;
                float av = da + ba0;
                float sp = (av > 20.f) ? av : log1pf(__expf(av));
                a8[p] = sp * (1.f / SCALE);
                float sx = 1.f / (1.f + __expf(-(d0 + bs0)));
                float sy = 1.f / (1.f + __expf(-(d1 + bs1)));
                isx[p] = 0.5f / (sx * sx);
                isy[p] = 0.5f / (sy * sy);
            }
        }
    }
}

// ---------------------------------------------------------------------------
// Kernel 1b: vb [token][dh] -> vT [b][dh][token] via LDS transpose.
// ---------------------------------------------------------------------------
__global__ __launch_bounds__(256) void vtrans_kernel(
    const unsigned short* __restrict__ vb, unsigned short* __restrict__ vT)
{
    __shared__ unsigned short tile[64][LDP];   // [dh][token]
    const int t  = threadIdx.x;
    const int bb = blockIdx.y;
    const int t0 = blockIdx.x * 64;

#pragma unroll
    for (int it = 0; it < 2; ++it) {
        int lin = t + it * 256;
        int tok = lin >> 3;
        int d0  = (lin & 7) * 8;
        short8v v8 = {0, 0, 0, 0, 0, 0, 0, 0};
        if (t0 + tok < TDIM)
            v8 = *(const short8v*)&vb[((size_t)bb * TDIM + t0 + tok) * 64 + d0];
        union { short8v v; unsigned short s[8]; } u; u.v = v8;
#pragma unroll
        for (int j = 0; j < 8; ++j) tile[d0 + j][tok] = u.s[j];
    }
    __syncthreads();

    const int dh = t >> 2;
    const int ch = t & 3;
    short8v o0 = *(const short8v*)&tile[dh][ch * 16];
    short8v o1 = *(const short8v*)&tile[dh][ch * 16 + 8];
    size_t dst = ((size_t)bb * 64 + dh) * VTLD + t0 + ch * 16;
    *(short8v*)&vT[dst]     = o0;
    *(short8v*)&vT[dst + 8] = o1;
}

// ---------------------------------------------------------------------------
// Kernel 2: MFMA flash attention, v3: single barrier per tile, double-buffered
// K/V staging with issue-early/write-late; DPP softmax; Q direct from global.
// ---------------------------------------------------------------------------
__global__ __launch_bounds__(256) void attn_mfma_kernel(
    const unsigned short* __restrict__ qb, const unsigned short* __restrict__ kb,
    const unsigned short* __restrict__ vT,
    const float* __restrict__ a8, const float* __restrict__ isx,
    const float* __restrict__ isy, float* __restrict__ out)
{
    __shared__ unsigned short Ks[2][64][LDP];
    __shared__ unsigned short Vt[2][64][LDP];   // [dh][key]
    __shared__ unsigned short Pt[4][16][LDP];   // per-wave [q][key]

    const int t  = threadIdx.x;
    const int wv = t >> 6;
    const int ln = t & 63;
    const int lq = ln >> 4;
    const int lr = ln & 15;
    const int bb = blockIdx.y;
    const int q0 = blockIdx.x * 64;

    // ---- Q fragments direct from global (rows clamped; results masked) ----
    const int qrow = min(q0 + wv * 16 + lr, TDIM - 1);
    const size_t qbase = ((size_t)bb * TDIM + qrow) * 64;
    const short8v aq0 = *(const short8v*)&qb[qbase + lq * 8];
    const short8v aq1 = *(const short8v*)&qb[qbase + 32 + lq * 8];

    // ---- per-reg query metadata ----
    float a8q[4], sxq[4], syq[4], qpy[4], qpx[4];
    bool  hasS[4];
#pragma unroll
    for (int reg = 0; reg < 4; ++reg) {
        int qg = q0 + wv * 16 + lq * 4 + reg;
        hasS[reg] = false;
        a8q[reg] = 0.f; sxq[reg] = 0.f; syq[reg] = 0.f; qpy[reg] = 0.f; qpx[reg] = 0.f;
        if (qg >= 1 && qg < TDIM) {
            int qp = qg - 1;
            hasS[reg] = true;
            a8q[reg] = a8 [bb * TPATCH + qp];
            sxq[reg] = isx[bb * TPATCH + qp];
            syq[reg] = isy[bb * TPATCH + qp];
            qpy[reg] = (float)(qp >> 5);
            qpx[reg] = (float)(qp & 31);
        }
    }

    float m[4]  = {-1e30f, -1e30f, -1e30f, -1e30f};
    float l[4]  = {0.f, 0.f, 0.f, 0.f};
    f32x4 oacc[4];
#pragma unroll
    for (int ni = 0; ni < 4; ++ni) oacc[ni] = (f32x4){0.f, 0.f, 0.f, 0.f};

    // ---- K/V staging maps ----
    const int sk_row = t >> 3;          // 0..31 (it adds 32)
    const int sk_d0  = (t & 7) * 8;
    short8v rk[2], rv[2];

#define ALOAD(KT0)                                                             \
    do {                                                                       \
        _Pragma("unroll") for (int it = 0; it < 2; ++it) {                     \
            int key = sk_row + 32 * it;                                        \
            int kg  = (KT0) + key;                                             \
            rk[it] = (kg < TDIM)                                               \
                ? *(const short8v*)&kb[((size_t)bb * TDIM + kg) * 64 + sk_d0]  \
                : (short8v){0, 0, 0, 0, 0, 0, 0, 0};                           \
            rv[it] = *(const short8v*)&vT[((size_t)bb * 64 + key) * VTLD +     \
                                          (KT0) + sk_d0];                      \
        }                                                                      \
    } while (0)

#define ASTORE(BUF)                                                            \
    do {                                                                       \
        _Pragma("unroll") for (int it = 0; it < 2; ++it) {                     \
            *(short8v*)&Ks[BUF][sk_row + 32 * it][sk_d0] = rk[it];             \
            *(short8v*)&Vt[BUF][sk_row + 32 * it][sk_d0] = rv[it];             \
        }                                                                      \
    } while (0)

    // prologue: stage tile 0
    ALOAD(0);
    ASTORE(0);
    __syncthreads();

    for (int tile = 0; tile < NTILES; ++tile) {
        const int kt0 = tile * 64;
        const int buf = tile & 1;
        if (tile + 1 < NTILES) ALOAD(kt0 + 64);        // issue early

        // ---- scores: S = Q K^T ----
        f32x4 sac[4];
#pragma unroll
        for (int ni = 0; ni < 4; ++ni) sac[ni] = (f32x4){0.f, 0.f, 0.f, 0.f};
#pragma unroll
        for (int ni = 0; ni < 4; ++ni) {
            short8v b0 = *(const short8v*)&Ks[buf][16 * ni + lr][lq * 8];
            short8v b1 = *(const short8v*)&Ks[buf][16 * ni + lr][32 + lq * 8];
            sac[ni] = __builtin_amdgcn_mfma_f32_16x16x32_bf16(aq0, b0, sac[ni], 0, 0, 0);
            sac[ni] = __builtin_amdgcn_mfma_f32_16x16x32_bf16(aq1, b1, sac[ni], 0, 0, 0);
        }

        // ---- bias + mask ----
#pragma unroll
        for (int ni = 0; ni < 4; ++ni) {
            int key = kt0 + 16 * ni + lr;
            int kp  = key - 1;
            float ky = (float)(kp >> 5);
            float kx = (float)(kp & 31);
            bool kvalid = (key >= 1) && (key < TDIM);
#pragma unroll
            for (int reg = 0; reg < 4; ++reg) {
                float z = sac[ni][reg] * (1.f / SCALE);
                if (kvalid && hasS[reg]) {
                    float dy = qpy[reg] - ky;
                    float dx = qpx[reg] - kx;
                    z += a8q[reg] * __expf(-(dx * dx * sxq[reg] + dy * dy * syq[reg]));
                }
                if (key >= TDIM) z = -1e30f;
                sac[ni][reg] = z;
            }
        }

        // ---- online softmax (DPP reductions) ----
        float scf[4];
#pragma unroll
        for (int reg = 0; reg < 4; ++reg) {
            float mx = fmaxf(fmaxf(sac[0][reg], sac[1][reg]),
                             fmaxf(sac[2][reg], sac[3][reg]));
            mx = red16_max(mx);
            float mn = fmaxf(m[reg], mx);
            scf[reg] = __expf(m[reg] - mn);
            m[reg] = mn;
            float ts = 0.f;
#pragma unroll
            for (int ni = 0; ni < 4; ++ni) {
                float pp = __expf(sac[ni][reg] - mn);
                sac[ni][reg] = pp;
                ts += pp;
            }
            ts = red16_sum(ts);
            l[reg] = l[reg] * scf[reg] + ts;
        }
#pragma unroll
        for (int ni = 0; ni < 4; ++ni)
#pragma unroll
            for (int reg = 0; reg < 4; ++reg)
                oacc[ni][reg] *= scf[reg];

        // ---- publish P (wave-private tile, no barrier needed) ----
#pragma unroll
        for (int ni = 0; ni < 4; ++ni)
#pragma unroll
            for (int reg = 0; reg < 4; ++reg)
                Pt[wv][lq * 4 + reg][16 * ni + lr] = f2bf(sac[ni][reg]);

        // ---- PV: O += P V ----
#pragma unroll
        for (int ks = 0; ks < 2; ++ks) {
            short8v pa = *(const short8v*)&Pt[wv][lr][ks * 32 + lq * 8];
#pragma unroll
            for (int ni = 0; ni < 4; ++ni) {
                short8v bv = *(const short8v*)&Vt[buf][16 * ni + lr][ks * 32 + lq * 8];
                oacc[ni] = __builtin_amdgcn_mfma_f32_16x16x32_bf16(pa, bv, oacc[ni], 0, 0, 0);
            }
        }

        if (tile + 1 < NTILES) ASTORE(buf ^ 1);        // vmcnt wait lands here
        __syncthreads();
    }
#undef ALOAD
#undef ASTORE

    // ---- epilogue ----
#pragma unroll
    for (int reg = 0; reg < 4; ++reg) {
        int qg = q0 + wv * 16 + lq * 4 + reg;
        if (qg < TDIM) {
            float rl = 1.f / l[reg];
#pragma unroll
            for (int ni = 0; ni < 4; ++ni)
                out[((size_t)bb * TDIM + qg) * 64 + 16 * ni + lr] = oacc[ni][reg] * rl;
        }
    }
}

extern "C" void kernel_launch(void* const* d_in, const int* in_sizes, int n_in,
                              void* d_out, int out_size, void* d_ws, size_t ws_size,
                              hipStream_t stream)
{
    const float* x    = (const float*)d_in[0];
    const float* Wq   = (const float*)d_in[1];
    const float* Wk   = (const float*)d_in[2];
    const float* Wv   = (const float*)d_in[3];
    const float* gq   = (const float*)d_in[4];
    const float* bq   = (const float*)d_in[5];
    const float* gk   = (const float*)d_in[6];
    const float* bk   = (const float*)d_in[7];
    const float* Wsig = (const float*)d_in[8];
    const float* bsig = (const float*)d_in[9];
    const float* Wa   = (const float*)d_in[10];
    const float* ba   = (const float*)d_in[11];
    float* out = (float*)d_out;

    // ---- workspace layout ----
    char* w = (char*)d_ws;
    const size_t NQ = (size_t)NROW * 64;
    unsigned short* qb = (unsigned short*)w;   w += NQ * 2;
    unsigned short* kb = (unsigned short*)w;   w += NQ * 2;
    unsigned short* vb = (unsigned short*)w;   w += NQ * 2;
    unsigned short* vT = (unsigned short*)w;   w += (size_t)BDIM * 64 * VTLD * 2;
    float* a8  = (float*)w;                    w += (size_t)BDIM * TPATCH * 4;
    float* isx = (float*)w;                    w += (size_t)BDIM * TPATCH * 4;
    float* isy = (float*)w;                    w += (size_t)BDIM * TPATCH * 4;
    unsigned short* wT = (unsigned short*)w;   w += (size_t)192 * DDIM * 2;

    hipLaunchKernelGGL(prep_w_kernel, dim3(192), dim3(256), 0, stream,
                       Wq, Wk, Wv, wT);

    const int nblk1 = (NROW + 63) / 64;   // 513
    hipLaunchKernelGGL(qkv_tile_kernel, dim3(nblk1), dim3(256), 0, stream,
                       x, wT, gq, bq, gk, bk, Wsig, bsig, Wa, ba,
                       qb, kb, vb, a8, isx, isy);

    hipLaunchKernelGGL(vtrans_kernel, dim3(17, BDIM), dim3(256), 0, stream,
                       vb, vT);

    hipLaunchKernelGGL(attn_mfma_kernel, dim3(17, BDIM), dim3(256), 0, stream,
                       qb, kb, vT, a8, isx, isy, out);
}

// Round 8
// 95.546 us; speedup vs baseline: 1.1357x; 1.1357x over previous
//
#include <hip/hip_runtime.h>
#include <hip/hip_bf16.h>
#include <math.h>

#define BDIM 32
#define TDIM 1025
#define DDIM 768
#define GRIDW 32
#define TPATCH 1024
#define SCALE 8.0f
#define EPSLN 1e-5f
#define NROW (BDIM * TDIM)   // 32800
#define VTLD 1088            // vT row stride (elements, 16B-aligned, >= 1024+64)
#define LDP  72              // LDS row stride for attn tiles
#define LDQ  40              // LDS row stride for qkv tiles (BK=32)
#define NTILES 17

typedef __attribute__((ext_vector_type(8))) short short8v;   // 8 bf16 (4 VGPRs)
typedef __attribute__((ext_vector_type(4))) float f32x4;     // MFMA C/D frag

__device__ __forceinline__ unsigned short f2bf(float f) {
    unsigned int u = __float_as_uint(f);
    u += 0x7FFFu + ((u >> 16) & 1u);      // round-to-nearest-even
    return (unsigned short)(u >> 16);
}

__device__ __forceinline__ ushort4 pack4(float4 a) {
    ushort4 r;
    r.x = f2bf(a.x); r.y = f2bf(a.y); r.z = f2bf(a.z); r.w = f2bf(a.w);
    return r;
}

// Workgroup barrier WITHOUT the vmcnt(0) drain __syncthreads() imposes.
// lgkmcnt(0) makes our ds_writes visible; global loads stay in flight
// across the barrier (counted vmcnt waits are inserted by the compiler
// exactly where the loaded registers are consumed).
__device__ __forceinline__ void wg_barrier() {
    asm volatile("s_waitcnt lgkmcnt(0)" ::: "memory");
    __builtin_amdgcn_s_barrier();
    __builtin_amdgcn_sched_barrier(0);
}

// ---- 16-lane (DPP-row) reductions on the VALU pipe (no LDS latency) ----
template<int CTRL>
__device__ __forceinline__ float dpp_f(float x) {
    return __int_as_float(__builtin_amdgcn_update_dpp(
        __float_as_int(x), __float_as_int(x), CTRL, 0xF, 0xF, true));
}
__device__ __forceinline__ float red16_max(float x) {
    x = fmaxf(x, dpp_f<0xB1>(x));    // quad_perm xor1
    x = fmaxf(x, dpp_f<0x4E>(x));    // quad_perm xor2
    x = fmaxf(x, dpp_f<0x124>(x));   // row_ror:4
    x = fmaxf(x, dpp_f<0x128>(x));   // row_ror:8
    return x;
}
__device__ __forceinline__ float red16_sum(float x) {
    x += dpp_f<0xB1>(x);
    x += dpp_f<0x4E>(x);
    x += dpp_f<0x124>(x);
    x += dpp_f<0x128>(x);
    return x;
}

// ---------------------------------------------------------------------------
// Kernel 0: W -> bf16, transposed: wT[c][k], c = 0..191 (q|k|v), k = 0..767
// ---------------------------------------------------------------------------
__global__ __launch_bounds__(256) void prep_w_kernel(
    const float* __restrict__ Wq, const float* __restrict__ Wk,
    const float* __restrict__ Wv, unsigned short* __restrict__ wT)
{
    const int c = blockIdx.x;                  // 0..191
    const float* W = (c < 64) ? Wq : (c < 128) ? Wk : Wv;
    const int cc = c & 63;
    for (int k = threadIdx.x; k < DDIM; k += 256)
        wT[(size_t)c * DDIM + k] = f2bf(W[(size_t)k * 64 + cc]);
}

// ---------------------------------------------------------------------------
// Kernel 1: MFMA QKV projection + fused LN + heads.
// 513 blocks x 4 waves; block = 64 rows x 192 cols; BK=32, 24 K-steps.
// Distance-2 register pipeline (set A = even k -> buf0, set B = odd k -> buf1)
// with raw barriers: global loads stay in flight across ~2 compute phases;
// reg->LDS stores use compiler-counted vmcnt (never 0 in the loop).
// ---------------------------------------------------------------------------
__global__ __launch_bounds__(256) void qkv_tile_kernel(
    const float* __restrict__ x, const unsigned short* __restrict__ wT,
    const float* __restrict__ gq, const float* __restrict__ bq,
    const float* __restrict__ gk, const float* __restrict__ bk,
    const float* __restrict__ Wsig, const float* __restrict__ bsig,
    const float* __restrict__ Wa, const float* __restrict__ ba,
    unsigned short* __restrict__ qb, unsigned short* __restrict__ kb,
    unsigned short* __restrict__ vb,
    float* __restrict__ a8, float* __restrict__ isx, float* __restrict__ isy)
{
    __shared__ unsigned short As[2][64][LDQ];    // 10.2 KB
    __shared__ unsigned short Bs[2][192][LDQ];   // 30.7 KB

    const int t  = threadIdx.x;
    const int wv = t >> 6;
    const int ln = t & 63;
    const int lq = ln >> 4;
    const int lr = ln & 15;
    const int tok0 = blockIdx.x * 64;           // flat row (b*TDIM + ti)

    // A staging map: chunk c in [0,512): row=c>>3, 16B-seg=c&7 (float4)
    const int ar0 = t >> 3,          as0 = (t & 7) * 4;
    const int ar1 = (t + 256) >> 3,  as1 = ((t + 256) & 7) * 4;
    const float* la0 = x + (size_t)min(tok0 + ar0, NROW - 1) * DDIM + as0;
    const float* la1 = x + (size_t)min(tok0 + ar1, NROW - 1) * DDIM + as1;
    // B staging map: chunk c in [0,768): row=c>>2, seg=c&3 (short8)
    const int br0 = t >> 2,          bs0 = (t & 3) * 8;
    const int br1 = (t + 256) >> 2,  bs1 = ((t + 256) & 3) * 8;
    const int br2 = (t + 512) >> 2,  bs2 = ((t + 512) & 3) * 8;
    const unsigned short* lb0 = wT + (size_t)br0 * DDIM + bs0;
    const unsigned short* lb1 = wT + (size_t)br1 * DDIM + bs1;
    const unsigned short* lb2 = wT + (size_t)br2 * DDIM + bs2;

    float4  raA0, raA1, raB0, raB1;
    short8v rbA0, rbA1, rbA2, rbB0, rbB1, rbB2;

#define LOAD_SET_A(K0)                                                         \
    do {                                                                       \
        raA0 = *(const float4*)(la0 + (K0));                                   \
        raA1 = *(const float4*)(la1 + (K0));                                   \
        rbA0 = *(const short8v*)(lb0 + (K0));                                  \
        rbA1 = *(const short8v*)(lb1 + (K0));                                  \
        rbA2 = *(const short8v*)(lb2 + (K0));                                  \
    } while (0)
#define LOAD_SET_B(K0)                                                         \
    do {                                                                       \
        raB0 = *(const float4*)(la0 + (K0));                                   \
        raB1 = *(const float4*)(la1 + (K0));                                   \
        rbB0 = *(const short8v*)(lb0 + (K0));                                  \
        rbB1 = *(const short8v*)(lb1 + (K0));                                  \
        rbB2 = *(const short8v*)(lb2 + (K0));                                  \
    } while (0)
#define STORE_SET_A()                                                          \
    do {                                                                       \
        *(ushort4*)&As[0][ar0][as0] = pack4(raA0);                             \
        *(ushort4*)&As[0][ar1][as1] = pack4(raA1);                             \
        *(short8v*)&Bs[0][br0][bs0] = rbA0;                                    \
        *(short8v*)&Bs[0][br1][bs1] = rbA1;                                    \
        *(short8v*)&Bs[0][br2][bs2] = rbA2;                                    \
    } while (0)
#define STORE_SET_B()                                                          \
    do {                                                                       \
        *(ushort4*)&As[1][ar0][as0] = pack4(raB0);                             \
        *(ushort4*)&As[1][ar1][as1] = pack4(raB1);                             \
        *(short8v*)&Bs[1][br0][bs0] = rbB0;                                    \
        *(short8v*)&Bs[1][br1][bs1] = rbB1;                                    \
        *(short8v*)&Bs[1][br2][bs2] = rbB2;                                    \
    } while (0)
#define COMPUTE(BUF)                                                           \
    do {                                                                       \
        short8v af = *(const short8v*)&As[BUF][wv * 16 + lr][lq * 8];          \
        _Pragma("unroll") for (int ni = 0; ni < 12; ++ni) {                    \
            short8v bf = *(const short8v*)&Bs[BUF][16 * ni + lr][lq * 8];      \
            acc[ni] = __builtin_amdgcn_mfma_f32_16x16x32_bf16(af, bf,          \
                                                              acc[ni], 0, 0, 0); \
        }                                                                      \
    } while (0)

    f32x4 acc[12];
#pragma unroll
    for (int ni = 0; ni < 12; ++ni) acc[ni] = (f32x4){0.f, 0.f, 0.f, 0.f};

    // prologue: k0 -> set A, k1 -> set B
    LOAD_SET_A(0);
    LOAD_SET_B(32);
    STORE_SET_A();
    wg_barrier();

#pragma unroll
    for (int ks = 0; ks < 24; ks += 2) {
        // even step: compute k=ks from buf0
        if (ks + 2 < 24) LOAD_SET_A((ks + 2) * 32);   // in flight ~2 phases
        COMPUTE(0);
        STORE_SET_B();                                 // counted vmcnt here
        wg_barrier();
        // odd step: compute k=ks+1 from buf1
        if (ks + 3 < 24) LOAD_SET_B((ks + 3) * 32);
        COMPUTE(1);
        if (ks + 2 < 24) STORE_SET_A();
        wg_barrier();
    }
#undef LOAD_SET_A
#undef LOAD_SET_B
#undef STORE_SET_A
#undef STORE_SET_B
#undef COMPUTE

    // ---- epilogue: LN(q), LN(k), alpha/sigma head, writes ----
    float gqv[4], bqv[4], gkv[4], bkv[4], wav[4], ws0[4], ws1[4];
#pragma unroll
    for (int ni = 0; ni < 4; ++ni) {
        int c = lr + 16 * ni;
        gqv[ni] = gq[c]; bqv[ni] = bq[c];
        gkv[ni] = gk[c]; bkv[ni] = bk[c];
        wav[ni] = Wa[c];
        ws0[ni] = Wsig[2 * c];
        ws1[ni] = Wsig[2 * c + 1];
    }
    const float ba0 = ba[0], bs0c = bsig[0], bs1c = bsig[1];

#pragma unroll
    for (int reg = 0; reg < 4; ++reg) {
        const int tokr = tok0 + wv * 16 + lq * 4 + reg;

        float s1 = 0.f, s2 = 0.f;
#pragma unroll
        for (int ni = 0; ni < 4; ++ni) {
            float v = acc[ni][reg];
            s1 += v; s2 += v * v;
        }
        s1 = red16_sum(s1);
        s2 = red16_sum(s2);
        float mean = s1 * (1.f / 64.f);
        float var  = s2 * (1.f / 64.f) - mean * mean;
        float rstd = rsqrtf(var + EPSLN);
        float qn[4];
#pragma unroll
        for (int ni = 0; ni < 4; ++ni)
            qn[ni] = (acc[ni][reg] - mean) * rstd * gqv[ni] + bqv[ni];

        s1 = 0.f; s2 = 0.f;
#pragma unroll
        for (int ni = 0; ni < 4; ++ni) {
            float v = acc[4 + ni][reg];
            s1 += v; s2 += v * v;
        }
        s1 = red16_sum(s1);
        s2 = red16_sum(s2);
        mean = s1 * (1.f / 64.f);
        var  = s2 * (1.f / 64.f) - mean * mean;
        rstd = rsqrtf(var + EPSLN);
        float kn[4];
#pragma unroll
        for (int ni = 0; ni < 4; ++ni)
            kn[ni] = (acc[4 + ni][reg] - mean) * rstd * gkv[ni] + bkv[ni];

        float da = 0.f, d0 = 0.f, d1 = 0.f;
#pragma unroll
        for (int ni = 0; ni < 4; ++ni) {
            da += qn[ni] * wav[ni];
            d0 += qn[ni] * ws0[ni];
            d1 += qn[ni] * ws1[ni];
        }
        da = red16_sum(da);
        d0 = red16_sum(d0);
        d1 = red16_sum(d1);

        if (tokr < NROW) {
            size_t base = (size_t)tokr * 64;
            int bidx = tokr / TDIM;
            int ti   = tokr - bidx * TDIM;
#pragma unroll
            for (int ni = 0; ni < 4; ++ni) {
                int c = lr + 16 * ni;
                qb[base + c] = f2bf(qn[ni]);
                kb[base + c] = f2bf(kn[ni]);
                vb[base + c] = f2bf(acc[8 + ni][reg]);
            }
            if (lr == 0 && ti >= 1) {
                int p = bidx * TPATCH + ti - 1;
                float av = da + ba0;
                float sp = (av > 20.f) ? av : log1pf(__expf(av));
                a8[p] = sp * (1.f / SCALE);
                float sx = 1.f / (1.f + __expf(-(d0 + bs0c)));
                float sy = 1.f / (1.f + __expf(-(d1 + bs1c)));
                isx[p] = 0.5f / (sx * sx);
                isy[p] = 0.5f / (sy * sy);
            }
        }
    }
}

// ---------------------------------------------------------------------------
// Kernel 1b: vb [token][dh] -> vT [b][dh][token] via LDS transpose.
// ---------------------------------------------------------------------------
__global__ __launch_bounds__(256) void vtrans_kernel(
    const unsigned short* __restrict__ vb, unsigned short* __restrict__ vT)
{
    __shared__ unsigned short tile[64][LDP];   // [dh][token]
    const int t  = threadIdx.x;
    const int bb = blockIdx.y;
    const int t0 = blockIdx.x * 64;

#pragma unroll
    for (int it = 0; it < 2; ++it) {
        int lin = t + it * 256;
        int tok = lin >> 3;
        int d0  = (lin & 7) * 8;
        short8v v8 = {0, 0, 0, 0, 0, 0, 0, 0};
        if (t0 + tok < TDIM)
            v8 = *(const short8v*)&vb[((size_t)bb * TDIM + t0 + tok) * 64 + d0];
        union { short8v v; unsigned short s[8]; } u; u.v = v8;
#pragma unroll
        for (int j = 0; j < 8; ++j) tile[d0 + j][tok] = u.s[j];
    }
    __syncthreads();

    const int dh = t >> 2;
    const int ch = t & 3;
    short8v o0 = *(const short8v*)&tile[dh][ch * 16];
    short8v o1 = *(const short8v*)&tile[dh][ch * 16 + 8];
    size_t dst = ((size_t)bb * 64 + dh) * VTLD + t0 + ch * 16;
    *(short8v*)&vT[dst]     = o0;
    *(short8v*)&vT[dst + 8] = o1;
}

// ---------------------------------------------------------------------------
// Kernel 2: MFMA flash attention: raw barriers (no vmcnt drain), double-
// buffered K/V with issue-early/write-late; DPP softmax; Q direct from global.
// ---------------------------------------------------------------------------
__global__ __launch_bounds__(256) void attn_mfma_kernel(
    const unsigned short* __restrict__ qb, const unsigned short* __restrict__ kb,
    const unsigned short* __restrict__ vT,
    const float* __restrict__ a8, const float* __restrict__ isx,
    const float* __restrict__ isy, float* __restrict__ out)
{
    __shared__ unsigned short Ks[2][64][LDP];
    __shared__ unsigned short Vt[2][64][LDP];   // [dh][key]
    __shared__ unsigned short Pt[4][16][LDP];   // per-wave [q][key]

    const int t  = threadIdx.x;
    const int wv = t >> 6;
    const int ln = t & 63;
    const int lq = ln >> 4;
    const int lr = ln & 15;
    const int bb = blockIdx.y;
    const int q0 = blockIdx.x * 64;

    // ---- Q fragments direct from global (rows clamped; results masked) ----
    const int qrow = min(q0 + wv * 16 + lr, TDIM - 1);
    const size_t qbase = ((size_t)bb * TDIM + qrow) * 64;
    const short8v aq0 = *(const short8v*)&qb[qbase + lq * 8];
    const short8v aq1 = *(const short8v*)&qb[qbase + 32 + lq * 8];

    // ---- per-reg query metadata ----
    float a8q[4], sxq[4], syq[4], qpy[4], qpx[4];
    bool  hasS[4];
#pragma unroll
    for (int reg = 0; reg < 4; ++reg) {
        int qg = q0 + wv * 16 + lq * 4 + reg;
        hasS[reg] = false;
        a8q[reg] = 0.f; sxq[reg] = 0.f; syq[reg] = 0.f; qpy[reg] = 0.f; qpx[reg] = 0.f;
        if (qg >= 1 && qg < TDIM) {
            int qp = qg - 1;
            hasS[reg] = true;
            a8q[reg] = a8 [bb * TPATCH + qp];
            sxq[reg] = isx[bb * TPATCH + qp];
            syq[reg] = isy[bb * TPATCH + qp];
            qpy[reg] = (float)(qp >> 5);
            qpx[reg] = (float)(qp & 31);
        }
    }

    float m[4]  = {-1e30f, -1e30f, -1e30f, -1e30f};
    float l[4]  = {0.f, 0.f, 0.f, 0.f};
    f32x4 oacc[4];
#pragma unroll
    for (int ni = 0; ni < 4; ++ni) oacc[ni] = (f32x4){0.f, 0.f, 0.f, 0.f};

    // ---- K/V staging maps ----
    const int sk_row = t >> 3;          // 0..31 (it adds 32)
    const int sk_d0  = (t & 7) * 8;
    short8v rk[2], rv[2];

#define ALOAD(KT0)                                                             \
    do {                                                                       \
        _Pragma("unroll") for (int it = 0; it < 2; ++it) {                     \
            int key = sk_row + 32 * it;                                        \
            int kg  = (KT0) + key;                                             \
            rk[it] = (kg < TDIM)                                               \
                ? *(const short8v*)&kb[((size_t)bb * TDIM + kg) * 64 + sk_d0]  \
                : (short8v){0, 0, 0, 0, 0, 0, 0, 0};                           \
            rv[it] = *(const short8v*)&vT[((size_t)bb * 64 + key) * VTLD +     \
                                          (KT0) + sk_d0];                      \
        }                                                                      \
    } while (0)

#define ASTORE(BUF)                                                            \
    do {                                                                       \
        _Pragma("unroll") for (int it = 0; it < 2; ++it) {                     \
            *(short8v*)&Ks[BUF][sk_row + 32 * it][sk_d0] = rk[it];             \
            *(short8v*)&Vt[BUF][sk_row + 32 * it][sk_d0] = rv[it];             \
        }                                                                      \
    } while (0)

    // prologue: stage tile 0
    ALOAD(0);
    ASTORE(0);
    wg_barrier();

    for (int tile = 0; tile < NTILES; ++tile) {
        const int kt0 = tile * 64;
        const int buf = tile & 1;
        if (tile + 1 < NTILES) ALOAD(kt0 + 64);        // issue early

        // ---- scores: S = Q K^T ----
        f32x4 sac[4];
#pragma unroll
        for (int ni = 0; ni < 4; ++ni) sac[ni] = (f32x4){0.f, 0.f, 0.f, 0.f};
#pragma unroll
        for (int ni = 0; ni < 4; ++ni) {
            short8v b0 = *(const short8v*)&Ks[buf][16 * ni + lr][lq * 8];
            short8v b1 = *(const short8v*)&Ks[buf][16 * ni + lr][32 + lq * 8];
            sac[ni] = __builtin_amdgcn_mfma_f32_16x16x32_bf16(aq0, b0, sac[ni], 0, 0, 0);
            sac[ni] = __builtin_amdgcn_mfma_f32_16x16x32_bf16(aq1, b1, sac[ni], 0, 0, 0);
        }

        // ---- bias + mask ----
#pragma unroll
        for (int ni = 0; ni < 4; ++ni) {
            int key = kt0 + 16 * ni + lr;
            int kp  = key - 1;
            float ky = (float)(kp >> 5);
            float kx = (float)(kp & 31);
            bool kvalid = (key >= 1) && (key < TDIM);
#pragma unroll
            for (int reg = 0; reg < 4; ++reg) {
                float z = sac[ni][reg] * (1.f / SCALE);
                if (kvalid && hasS[reg]) {
                    float dy = qpy[reg] - ky;
                    float dx = qpx[reg] - kx;
                    z += a8q[reg] * __expf(-(dx * dx * sxq[reg] + dy * dy * syq[reg]));
                }
                if (key >= TDIM) z = -1e30f;
                sac[ni][reg] = z;
            }
        }

        // ---- online softmax (DPP reductions) ----
        float scf[4];
#pragma unroll
        for (int reg = 0; reg < 4; ++reg) {
            float mx = fmaxf(fmaxf(sac[0][reg], sac[1][reg]),
                             fmaxf(sac[2][reg], sac[3][reg]));
            mx = red16_max(mx);
            float mn = fmaxf(m[reg], mx);
            scf[reg] = __expf(m[reg] - mn);
            m[reg] = mn;
            float ts = 0.f;
#pragma unroll
            for (int ni = 0; ni < 4; ++ni) {
                float pp = __expf(sac[ni][reg] - mn);
                sac[ni][reg] = pp;
                ts += pp;
            }
            ts = red16_sum(ts);
            l[reg] = l[reg] * scf[reg] + ts;
        }
#pragma unroll
        for (int ni = 0; ni < 4; ++ni)
#pragma unroll
            for (int reg = 0; reg < 4; ++reg)
                oacc[ni][reg] *= scf[reg];

        // ---- publish P (wave-private tile, same-wave LDS FIFO) ----
#pragma unroll
        for (int ni = 0; ni < 4; ++ni)
#pragma unroll
            for (int reg = 0; reg < 4; ++reg)
                Pt[wv][lq * 4 + reg][16 * ni + lr] = f2bf(sac[ni][reg]);

        // ---- PV: O += P V ----
#pragma unroll
        for (int ks = 0; ks < 2; ++ks) {
            short8v pa = *(const short8v*)&Pt[wv][lr][ks * 32 + lq * 8];
#pragma unroll
            for (int ni = 0; ni < 4; ++ni) {
                short8v bv = *(const short8v*)&Vt[buf][16 * ni + lr][ks * 32 + lq * 8];
                oacc[ni] = __builtin_amdgcn_mfma_f32_16x16x32_bf16(pa, bv, oacc[ni], 0, 0, 0);
            }
        }

        if (tile + 1 < NTILES) ASTORE(buf ^ 1);        // counted vmcnt here
        wg_barrier();
    }
#undef ALOAD
#undef ASTORE

    // ---- epilogue ----
#pragma unroll
    for (int reg = 0; reg < 4; ++reg) {
        int qg = q0 + wv * 16 + lq * 4 + reg;
        if (qg < TDIM) {
            float rl = 1.f / l[reg];
#pragma unroll
            for (int ni = 0; ni < 4; ++ni)
                out[((size_t)bb * TDIM + qg) * 64 + 16 * ni + lr] = oacc[ni][reg] * rl;
        }
    }
}

extern "C" void kernel_launch(void* const* d_in, const int* in_sizes, int n_in,
                              void* d_out, int out_size, void* d_ws, size_t ws_size,
                              hipStream_t stream)
{
    const float* x    = (const float*)d_in[0];
    const float* Wq   = (const float*)d_in[1];
    const float* Wk   = (const float*)d_in[2];
    const float* Wv   = (const float*)d_in[3];
    const float* gq   = (const float*)d_in[4];
    const float* bq   = (const float*)d_in[5];
    const float* gk   = (const float*)d_in[6];
    const float* bk   = (const float*)d_in[7];
    const float* Wsig = (const float*)d_in[8];
    const float* bsig = (const float*)d_in[9];
    const float* Wa   = (const float*)d_in[10];
    const float* ba   = (const float*)d_in[11];
    float* out = (float*)d_out;

    // ---- workspace layout ----
    char* w = (char*)d_ws;
    const size_t NQ = (size_t)NROW * 64;
    unsigned short* qb = (unsigned short*)w;   w += NQ * 2;
    unsigned short* kb = (unsigned short*)w;   w += NQ * 2;
    unsigned short* vb = (unsigned short*)w;   w += NQ * 2;
    unsigned short* vT = (unsigned short*)w;   w += (size_t)BDIM * 64 * VTLD * 2;
    float* a8  = (float*)w;                    w += (size_t)BDIM * TPATCH * 4;
    float* isx = (float*)w;                    w += (size_t)BDIM * TPATCH * 4;
    float* isy = (float*)w;                    w += (size_t)BDIM * TPATCH * 4;
    unsigned short* wT = (unsigned short*)w;   w += (size_t)192 * DDIM * 2;

    hipLaunchKernelGGL(prep_w_kernel, dim3(192), dim3(256), 0, stream,
                       Wq, Wk, Wv, wT);

    const int nblk1 = (NROW + 63) / 64;   // 513
    hipLaunchKernelGGL(qkv_tile_kernel, dim3(nblk1), dim3(256), 0, stream,
                       x, wT, gq, bq, gk, bk, Wsig, bsig, Wa, ba,
                       qb, kb, vb, a8, isx, isy);

    hipLaunchKernelGGL(vtrans_kernel, dim3(17, BDIM), dim3(256), 0, stream,
                       vb, vT);

    hipLaunchKernelGGL(attn_mfma_kernel, dim3(17, BDIM), dim3(256), 0, stream,
                       qb, kb, vT, a8, isx, isy, out);
}